// Round 11
// baseline (45.254 us; speedup 1.0000x reference)
//
#include <hip/hip_runtime.h>
#include <hip/hip_bf16.h>

// mIoU loss, pair-key histogram, two-stage (no global atomics).
// Ledger:
//  R1: global atomics on 60 addrs -> 313us.
//  R2~R3: DS op mix irrelevant (42us invariant).
//  R4~R6: C-level MLP idioms defeated by allocator (VGPR 28/36/44).
//  R7 ablation: plain-load probe ~27us (~5 TB/s) -> load path is the wall.
//  R8~R10: global_load_lds DMA pipeline: 32.7-34.6us == 134MB @ ~4.1TB/s,
//      INVARIANT to pipeline depth (2 vs 4 slots), occupancy (8 vs 12
//      waves), atomic count (1 vs 2/px) -> DMA path BW-capped ~4.1 TB/s.
//      Corrected DS model: consume pipes total <8us; stream is everything.
//  R11: inline-asm loads. 16x asm-volatile global_load_dwordx4 (issue
//      order guaranteed by volatility), per-pair counted vmcnt(14..0)
//      with tied "+v" operands (consumers data-depend on post-wait
//      values, rule #18 sched_barrier), pair-key consume (R9). No
//      staging LDS. VGPR>=88 is the validity check.

#define NB      20
#define NKEY    (NB * NB)   // 400
#define NCOPY   16
#define BLK     256         // 4 waves
#define GRID_H  2048
#define PSTRIDE 64          // padded row per block in workspace
#define FAST_ITERS 8        // 2048*256*8 int4s == 16M pixels exactly

typedef int v4i __attribute__((ext_vector_type(4)));

__device__ __forceinline__ v4i ld16(const v4i* p) {
    v4i r;
    asm volatile("global_load_dwordx4 %0, %1, off" : "=&v"(r) : "v"(p));
    return r;
}

#define SB0() __builtin_amdgcn_sched_barrier(0)
// Counted wait; tied operands make every later use of a/b depend on the
// post-wait value, so no consumer can be hoisted above the wait.
#define WAITPAIR(N, a, b) \
    asm volatile("s_waitcnt vmcnt(" #N ")" : "+v"(a), "+v"(b) :: "memory")

__device__ __forceinline__ void consume4(v4i p, v4i t, unsigned* hist_cp) {
    // ONE fire-and-forget LDS atomic per pixel; key = pred*20+targ.
    atomicAdd(&hist_cp[(p.x * NB + t.x) * NCOPY], 1u);
    atomicAdd(&hist_cp[(p.y * NB + t.y) * NCOPY], 1u);
    atomicAdd(&hist_cp[(p.z * NB + t.z) * NCOPY], 1u);
    atomicAdd(&hist_cp[(p.w * NB + t.w) * NCOPY], 1u);
}

__global__ __launch_bounds__(BLK) void miou_hist_kernel(
        const v4i* __restrict__ preds, const v4i* __restrict__ targs,
        unsigned* __restrict__ partials, int n4, int fast) {
    __shared__ unsigned s_hist[NKEY * NCOPY];   // 25.6 KB
    const int tid  = threadIdx.x;
    const int wid  = tid >> 6;
    const int lane = tid & 63;

    for (int k = tid; k < NKEY * NCOPY; k += BLK) s_hist[k] = 0u;
    __syncthreads();

    unsigned* hist_cp = &s_hist[tid & (NCOPY - 1)];
    const int stride = gridDim.x * BLK;
    const int base   = blockIdx.x * BLK + tid;

    if (fast) {
        const v4i* pp = preds + base;
        const v4i* tp = targs + base;
        // Issue all 16 loads back-to-back (asm volatile order is binding).
        v4i p0 = ld16(pp);               v4i t0 = ld16(tp);
        v4i p1 = ld16(pp + 1 * stride);  v4i t1 = ld16(tp + 1 * stride);
        v4i p2 = ld16(pp + 2 * stride);  v4i t2 = ld16(tp + 2 * stride);
        v4i p3 = ld16(pp + 3 * stride);  v4i t3 = ld16(tp + 3 * stride);
        v4i p4 = ld16(pp + 4 * stride);  v4i t4 = ld16(tp + 4 * stride);
        v4i p5 = ld16(pp + 5 * stride);  v4i t5 = ld16(tp + 5 * stride);
        v4i p6 = ld16(pp + 6 * stride);  v4i t6 = ld16(tp + 6 * stride);
        v4i p7 = ld16(pp + 7 * stride);  v4i t7 = ld16(tp + 7 * stride);
        // Consume pairs as they land (vmcnt decrements in issue order).
        WAITPAIR(14, p0, t0); SB0(); consume4(p0, t0, hist_cp);
        WAITPAIR(12, p1, t1); SB0(); consume4(p1, t1, hist_cp);
        WAITPAIR(10, p2, t2); SB0(); consume4(p2, t2, hist_cp);
        WAITPAIR(8,  p3, t3); SB0(); consume4(p3, t3, hist_cp);
        WAITPAIR(6,  p4, t4); SB0(); consume4(p4, t4, hist_cp);
        WAITPAIR(4,  p5, t5); SB0(); consume4(p5, t5, hist_cp);
        WAITPAIR(2,  p6, t6); SB0(); consume4(p6, t6, hist_cp);
        WAITPAIR(0,  p7, t7); SB0(); consume4(p7, t7, hist_cp);
    } else {
        // Generic path for any shape (compiler-managed loads/waits).
        for (int i = base; i < n4; i += stride) {
            v4i pv = preds[i];
            v4i tv = targs[i];
            consume4(pv, tv, hist_cp);
        }
    }
    __syncthreads();

    // Marginals (NCOPY=16): wave w handles classes w, w+4, ..., <NB.
    //  pc[c] = 320 contiguous words at c*320 (all t, all copies)
    //  tc[c] = for p in 0..19: 16 words at (p*20+c)*16
    //  ic[c] = 16 words at (c*21)*16
    unsigned* dst = &partials[(size_t)blockIdx.x * PSTRIDE];
    for (int c = wid; c < NB; c += (BLK / 64)) {
        unsigned pcs = 0;
        #pragma unroll
        for (int k = 0; k < 5; ++k) pcs += s_hist[c * 320 + k * 64 + lane];

        unsigned tcs = 0;
        {
            const int cp = lane & 15;
            const int pb = lane >> 4;    // 0..3
            #pragma unroll
            for (int rep = 0; rep < 5; ++rep)
                tcs += s_hist[((pb + rep * 4) * NB + c) * NCOPY + cp];
        }
        unsigned ics = (lane < NCOPY) ? s_hist[(c * 21) * NCOPY + lane] : 0u;

        #pragma unroll
        for (int off = 32; off > 0; off >>= 1) {
            pcs += __shfl_xor(pcs, off);
            tcs += __shfl_xor(tcs, off);
            ics += __shfl_xor(ics, off);
        }
        if (lane == 0) {
            dst[c]          = pcs;
            dst[NB + c]     = tcs;
            dst[2 * NB + c] = ics;
        }
    }
}

// One block, 1024 threads. partials = nblocks rows x 16 int4 (coalesced).
__global__ __launch_bounds__(1024) void miou_reduce_kernel(
        const unsigned* __restrict__ partials, int nblocks,
        const int* __restrict__ nb_ptr, const int* __restrict__ smooth_ptr,
        float* __restrict__ out) {
    __shared__ unsigned s_tot[PSTRIDE];
    if (threadIdx.x < PSTRIDE) s_tot[threadIdx.x] = 0u;
    __syncthreads();

    const int col4 = threadIdx.x & 15;
    const int seg  = threadIdx.x >> 4;
    const int4* p4 = (const int4*)partials;

    unsigned ax = 0, ay = 0, az = 0, aw = 0;
    #pragma unroll 8
    for (int r = seg; r < nblocks; r += 64) {
        int4 v = p4[r * 16 + col4];
        ax += (unsigned)v.x; ay += (unsigned)v.y;
        az += (unsigned)v.z; aw += (unsigned)v.w;
    }
    atomicAdd(&s_tot[col4 * 4 + 0], ax);
    atomicAdd(&s_tot[col4 * 4 + 1], ay);
    atomicAdd(&s_tot[col4 * 4 + 2], az);
    atomicAdd(&s_tot[col4 * 4 + 3], aw);
    __syncthreads();

    if (threadIdx.x == 0) {
        const int   nb = *nb_ptr;
        const float s  = (float)(*smooth_ptr);
        float acc_iou = 0.0f;
        for (int c = 0; c < nb && c < NB; ++c) {
            float pc    = (float)s_tot[c];
            float tc    = (float)s_tot[NB + c];
            float inter = (float)s_tot[2 * NB + c];
            float uni   = pc + tc - inter;
            acc_iou += (inter + s) / (uni + s);
        }
        out[0] = 1.0f - acc_iou / (float)nb;
    }
}

extern "C" void kernel_launch(void* const* d_in, const int* in_sizes, int n_in,
                              void* d_out, int out_size, void* d_ws, size_t ws_size,
                              hipStream_t stream) {
    const v4i*  preds      = (const v4i*)d_in[0];
    const v4i*  targs      = (const v4i*)d_in[1];
    const int*  nb_ptr     = (const int*)d_in[2];
    const int*  smooth_ptr = (const int*)d_in[3];
    float*      out        = (float*)d_out;

    int n  = in_sizes[0];
    int n4 = n >> 2;  // 16M pixels, divisible by 4

    unsigned* partials = (unsigned*)d_ws;

    int grid = GRID_H;
    int max_grid = (n4 + BLK - 1) / BLK;
    if (grid > max_grid) grid = max_grid;
    size_t need_per_block = PSTRIDE * sizeof(unsigned);
    if ((size_t)grid * need_per_block > ws_size)
        grid = (int)(ws_size / need_per_block);

    // Fast path only for the exact bench shape (no tail).
    int fast = (grid == GRID_H) && (n4 == FAST_ITERS * GRID_H * BLK);

    miou_hist_kernel<<<grid, BLK, 0, stream>>>(preds, targs, partials, n4, fast);
    miou_reduce_kernel<<<1, 1024, 0, stream>>>(partials, grid, nb_ptr, smooth_ptr, out);
}

// Round 12
// 30.730 us; speedup vs baseline: 1.4727x; 1.4727x over previous
//
#include <hip/hip_runtime.h>
#include <hip/hip_bf16.h>

// mIoU loss, pair-key histogram, two-stage (no global atomics).
// Ledger:
//  R1: global atomics on 60 addrs -> 313us.
//  R2~R3: DS op mix irrelevant (42us invariant).
//  R4~R6: C-level MLP idioms defeated by allocator (VGPR 28/36/44).
//  R7 ablation: plain-load probe ~27us (~5 TB/s) -> load path is the wall.
//  R8: DMA 2-deep, 2 atomics/px, 16 waves/CU: 34.6us.
//  R9: DMA 2-deep, 1 atomic/px, NCOPY=32 zero-conflict, 8 waves/CU: 32.7us
//      (best). Effective in-flight only ~1.35KB/wave -> depth-limited.
//  R10: 4-deep BUT NCOPY=8 -> 1.26M bank conflicts ate the gain: 34.5us.
//  R11: inline-asm loads: allocator assigned overlapping dest regs +
//      hidden serializing waits (VGPR 40, not 88+): 45us. Reverted.
//  R12: the unconfounded combo: NCOPY=32 (zero-conflict) + NSLOT=4 deep
//      DMA (vmcnt(6) steady, counted drain 4/2/0) + BLK=512.
//      114KB LDS -> 1 block/CU = 8 waves, 8KB in flight/wave (2x R9).
//      Prologue DMAs issued before hist-init to hide first round-trip.

#define NB      20
#define NKEY    (NB * NB)   // 400
#define NCOPY   32
#define BLK     512         // 8 waves
#define NSLOT   4           // slot-pairs in flight
#define GRID_H  256         // exactly 1 block/CU
#define PSTRIDE 64          // padded row per block in workspace

// 16B-per-lane DMA: LDS dest = wave-uniform base + lane*16 (m97/m104).
__device__ __forceinline__ void dma16(const void* g, void* l) {
    __builtin_amdgcn_global_load_lds(
        (const __attribute__((address_space(1))) unsigned*)g,
        (__attribute__((address_space(3))) unsigned*)l, 16, 0, 0);
}

__device__ __forceinline__ void process_pix(int p, int t, unsigned* hist_cp) {
    // ONE fire-and-forget LDS atomic per pixel; key = pred*20+targ.
    atomicAdd(&hist_cp[(p * NB + t) * NCOPY], 1u);
}

__device__ __forceinline__ void process_vec(int4 pv, int4 tv, unsigned* hist_cp) {
    process_pix(pv.x, tv.x, hist_cp);
    process_pix(pv.y, tv.y, hist_cp);
    process_pix(pv.z, tv.z, hist_cp);
    process_pix(pv.w, tv.w, hist_cp);
}

__global__ __launch_bounds__(BLK) void miou_hist_kernel(
        const int4* __restrict__ preds, const int4* __restrict__ targs,
        unsigned* __restrict__ partials, int n4, int full_iters) {
    __shared__ unsigned s_hist[NKEY * NCOPY];   // 51.2 KB, bank = copy
    __shared__ int4 s_p[NSLOT][BLK];            // 32 KB staging
    __shared__ int4 s_t[NSLOT][BLK];            // 32 KB
    const int tid  = threadIdx.x;
    const int wid  = tid >> 6;
    const int lane = tid & 63;

    unsigned* hist_cp = &s_hist[tid & (NCOPY - 1)];
    const int CHUNK = gridDim.x * BLK;
    const int base  = blockIdx.x * BLK + tid;

    // Prologue DMAs FIRST: their latency hides behind init + syncthreads.
    if (full_iters >= NSLOT) {
        #pragma unroll
        for (int s = 0; s < NSLOT; ++s) {
            dma16(&preds[base + s * CHUNK], &s_p[s][wid * 64]);
            dma16(&targs[base + s * CHUNK], &s_t[s][wid * 64]);
        }
    }
    for (int k = tid; k < NKEY * NCOPY; k += BLK) s_hist[k] = 0u;
    __syncthreads();

// One pipeline step: wait for slot J's pair, read it, drain LDS reads,
// refill the slot for J+NSLOT, consume.
#define STEP(J, VM) do {                                              \
    const int slot_ = (J) & (NSLOT - 1);                              \
    asm volatile("s_waitcnt vmcnt(" #VM ")" ::: "memory");            \
    int4 pv_ = s_p[slot_][wid * 64 + lane];                           \
    int4 tv_ = s_t[slot_][wid * 64 + lane];                           \
    asm volatile("s_waitcnt lgkmcnt(0)" ::: "memory");                \
    if ((J) + NSLOT < full_iters) {                                   \
        dma16(&preds[base + ((J) + NSLOT) * CHUNK], &s_p[slot_][wid * 64]); \
        dma16(&targs[base + ((J) + NSLOT) * CHUNK], &s_t[slot_][wid * 64]); \
    }                                                                 \
    process_vec(pv_, tv_, hist_cp);                                   \
} while (0)

    if (full_iters >= NSLOT) {   // host guarantees full==0 or >=NSLOT
        int j = 0;
        for (; j < full_iters - (NSLOT - 1); ++j) STEP(j, 6);
        STEP(j, 4); ++j;    // counted drain: 2 pairs left in flight
        STEP(j, 2); ++j;    // 1 pair left
        STEP(j, 0);         // drained
    }
    // Tail (plain loads; covers remainders and tiny shapes).
    for (int i = base + full_iters * CHUNK; i < n4; i += CHUNK) {
        int4 pv = preds[i];
        int4 tv = targs[i];
        process_vec(pv, tv, hist_cp);
    }
#undef STEP
    __syncthreads();

    // Marginals (NCOPY=32): wave w handles classes w, w+8, ... <NB.
    //  pc[c] = 640 contiguous words at c*640 (all t, all copies)
    //  tc[c] = for p in 0..19: 32 words at (p*20+c)*32 (bank = copy: clean)
    //  ic[c] = 32 words at (c*21)*32
    unsigned* dst = &partials[(size_t)blockIdx.x * PSTRIDE];
    for (int c = wid; c < NB; c += (BLK / 64)) {
        unsigned pcs = 0;
        #pragma unroll
        for (int k = 0; k < 640; k += 64) pcs += s_hist[c * 640 + k + lane];

        unsigned tcs = 0;
        {
            const int copy = lane & 31;
            const int p0   = lane >> 5;   // 0 or 1
            #pragma unroll
            for (int p = 0; p < NB; p += 2)
                tcs += s_hist[((p + p0) * NB + c) * NCOPY + copy];
        }
        unsigned ics = (lane < NCOPY) ? s_hist[(c * 21) * NCOPY + lane] : 0u;

        #pragma unroll
        for (int off = 32; off > 0; off >>= 1) {
            pcs += __shfl_xor(pcs, off);
            tcs += __shfl_xor(tcs, off);
            ics += __shfl_xor(ics, off);
        }
        if (lane == 0) {
            dst[c]          = pcs;
            dst[NB + c]     = tcs;
            dst[2 * NB + c] = ics;
        }
    }
}

// One block, 1024 threads. partials = nblocks rows x 16 int4 (coalesced).
__global__ __launch_bounds__(1024) void miou_reduce_kernel(
        const unsigned* __restrict__ partials, int nblocks,
        const int* __restrict__ nb_ptr, const int* __restrict__ smooth_ptr,
        float* __restrict__ out) {
    __shared__ unsigned s_tot[PSTRIDE];
    if (threadIdx.x < PSTRIDE) s_tot[threadIdx.x] = 0u;
    __syncthreads();

    const int col4 = threadIdx.x & 15;
    const int seg  = threadIdx.x >> 4;
    const int4* p4 = (const int4*)partials;

    unsigned ax = 0, ay = 0, az = 0, aw = 0;
    #pragma unroll 8
    for (int r = seg; r < nblocks; r += 64) {
        int4 v = p4[r * 16 + col4];
        ax += (unsigned)v.x; ay += (unsigned)v.y;
        az += (unsigned)v.z; aw += (unsigned)v.w;
    }
    atomicAdd(&s_tot[col4 * 4 + 0], ax);
    atomicAdd(&s_tot[col4 * 4 + 1], ay);
    atomicAdd(&s_tot[col4 * 4 + 2], az);
    atomicAdd(&s_tot[col4 * 4 + 3], aw);
    __syncthreads();

    if (threadIdx.x == 0) {
        const int   nb = *nb_ptr;
        const float s  = (float)(*smooth_ptr);
        float acc_iou = 0.0f;
        for (int c = 0; c < nb && c < NB; ++c) {
            float pc    = (float)s_tot[c];
            float tc    = (float)s_tot[NB + c];
            float inter = (float)s_tot[2 * NB + c];
            float uni   = pc + tc - inter;
            acc_iou += (inter + s) / (uni + s);
        }
        out[0] = 1.0f - acc_iou / (float)nb;
    }
}

extern "C" void kernel_launch(void* const* d_in, const int* in_sizes, int n_in,
                              void* d_out, int out_size, void* d_ws, size_t ws_size,
                              hipStream_t stream) {
    const int4* preds      = (const int4*)d_in[0];
    const int4* targs      = (const int4*)d_in[1];
    const int*  nb_ptr     = (const int*)d_in[2];
    const int*  smooth_ptr = (const int*)d_in[3];
    float*      out        = (float*)d_out;

    int n  = in_sizes[0];
    int n4 = n >> 2;  // 16M pixels, divisible by 4

    unsigned* partials = (unsigned*)d_ws;

    int grid = GRID_H;
    int max_grid = (n4 + BLK - 1) / BLK;
    if (grid > max_grid) grid = max_grid;
    size_t need_per_block = PSTRIDE * sizeof(unsigned);
    if ((size_t)grid * need_per_block > ws_size)
        grid = (int)(ws_size / need_per_block);

    int chunk = grid * BLK;
    int full  = (chunk > 0) ? (n4 / chunk) : 0;
    if (full < NSLOT) full = 0;   // tiny shapes -> tail path handles all

    miou_hist_kernel<<<grid, BLK, 0, stream>>>(preds, targs, partials, n4, full);
    miou_reduce_kernel<<<1, 1024, 0, stream>>>(partials, grid, nb_ptr, smooth_ptr, out);
}